// Round 1
// baseline (1449.194 us; speedup 1.0000x reference)
//
#include <hip/hip_runtime.h>
#include <cstdint>
#include <cstddef>

#define NODES 20000
#define NEDGE 320000

// ---------------- degree / normalization ----------------

__global__ void k_deg_init(float* __restrict__ deg) {
  int i = blockIdx.x * blockDim.x + threadIdx.x;
  if (i < NODES) deg[i] = 1.0f;  // self loop contributes 1 to every node
}

__global__ void k_deg_acc(const int* __restrict__ ei, float* __restrict__ deg) {
  int i = blockIdx.x * blockDim.x + threadIdx.x;
  if (i < NEDGE) atomicAdd(&deg[ei[NEDGE + i]], 1.0f);  // col = targets
}

__global__ void k_dis(float* __restrict__ deg) {
  int i = blockIdx.x * blockDim.x + threadIdx.x;
  if (i < NODES) deg[i] = rsqrtf(deg[i]);  // deg >= 1 always (self loop)
}

// ---------------- linear + pre-scale by dis[n] ----------------
// hs[n][b][c] = dis[n] * sum_k x[b][n][k] * lin_w[c][k];  agg initialized = hs
// (self-loop term: final out = dis[col]*(sum_in hs[row] + hs[col]))
__global__ void k_lin(const float* __restrict__ x, const float* __restrict__ lin_w,
                      const float* __restrict__ dis, float* __restrict__ hs,
                      float* __restrict__ agg) {
  __shared__ float xs[32][65];
  __shared__ float ws[64][65];
  int t = threadIdx.x;
  int n0 = blockIdx.x * 8;
  for (int i = t; i < 64 * 64; i += 256) ws[i >> 6][i & 63] = lin_w[i];
  for (int i = t; i < 32 * 64; i += 256) {
    int r = i >> 6, k = i & 63;
    int b = r & 3, n = n0 + (r >> 2);
    xs[r][k] = x[((size_t)b * NODES + n) * 64 + k];
  }
  __syncthreads();
  int oc = t & 63, rb = t >> 6;
  float acc[8];
#pragma unroll
  for (int j = 0; j < 8; ++j) acc[j] = 0.f;
  for (int k = 0; k < 64; ++k) {
    float wv = ws[oc][k];
#pragma unroll
    for (int j = 0; j < 8; ++j) acc[j] += xs[rb + 4 * j][k] * wv;
  }
#pragma unroll
  for (int j = 0; j < 8; ++j) {
    int r = rb + 4 * j;                 // row r <-> (n = n0 + (r>>2), b = r&3)
    int n = n0 + (r >> 2);
    float v = acc[j] * dis[n];
    size_t o = ((size_t)(n0 * 4) + r) * 64 + oc;  // (n*4+b)*64 + oc
    hs[o] = v;
    agg[o] = v;
  }
}

// ---------------- scatter-add: one wave per edge, 64 lanes x float4 ----------------
__global__ void k_scatter(const int* __restrict__ ei, const float* __restrict__ hs,
                          float* __restrict__ agg) {
  int g = blockIdx.x * blockDim.x + threadIdx.x;
  int e = g >> 6;
  int lane = g & 63;
  if (e >= NEDGE) return;
  int r = ei[e];          // source
  int c = ei[NEDGE + e];  // target
  const float4* src = (const float4*)(hs + (size_t)r * 256);
  float4 v = src[lane];
  float* dst = agg + (size_t)c * 256 + lane * 4;
  atomicAdd(dst + 0, v.x);
  atomicAdd(dst + 1, v.y);
  atomicAdd(dst + 2, v.z);
  atomicAdd(dst + 3, v.w);
}

// ---------------- sigmoid + matmul chain + concat + last + relu ----------------
// per block: 8 nodes -> 32 rows (r = n_local*4 + b) of C=64
__global__ void k_post(const float* __restrict__ agg, const float* __restrict__ dis,
                       const float* __restrict__ bias,
                       const float* __restrict__ up1, const float* __restrict__ up2,
                       const float* __restrict__ lo1, const float* __restrict__ lo2,
                       const float* __restrict__ lastw, float* __restrict__ out) {
  __shared__ float fst[32][65];
  __shared__ float tmp[32][65];
  __shared__ float comb[32][129];
  __shared__ float wb[4160];  // 64x65 (64-wide stages) or 32x129 (last chunks)
  int t = threadIdx.x;
  int n0 = blockIdx.x * 8;

  // fst = sigmoid(agg * dis + bias); agg tile is contiguous [n0*256 .. +2048)
  for (int i = t; i < 32 * 64; i += 256) {
    int r = i >> 6, k = i & 63;
    int n = n0 + (r >> 2);
    float v = agg[(size_t)n0 * 256 + i] * dis[n] + bias[k];
    fst[r][k] = 1.f / (1.f + __expf(-v));
  }
  for (int i = t; i < 4096; i += 256) wb[(i >> 6) * 65 + (i & 63)] = up1[i];
  __syncthreads();

  int oc = t & 63, rb = t >> 6;
  float acc[8];

  // tmp = fst @ up1^T
#pragma unroll
  for (int j = 0; j < 8; ++j) acc[j] = 0.f;
  for (int k = 0; k < 64; ++k) {
    float wv = wb[oc * 65 + k];
#pragma unroll
    for (int j = 0; j < 8; ++j) acc[j] += fst[rb + 4 * j][k] * wv;
  }
#pragma unroll
  for (int j = 0; j < 8; ++j) tmp[rb + 4 * j][oc] = acc[j];
  __syncthreads();

  // comb[:, 0:64] = tmp @ up2^T
  for (int i = t; i < 4096; i += 256) wb[(i >> 6) * 65 + (i & 63)] = up2[i];
  __syncthreads();
#pragma unroll
  for (int j = 0; j < 8; ++j) acc[j] = 0.f;
  for (int k = 0; k < 64; ++k) {
    float wv = wb[oc * 65 + k];
#pragma unroll
    for (int j = 0; j < 8; ++j) acc[j] += tmp[rb + 4 * j][k] * wv;
  }
#pragma unroll
  for (int j = 0; j < 8; ++j) comb[rb + 4 * j][oc] = acc[j];
  __syncthreads();

  // tmp = fst @ lo1^T
  for (int i = t; i < 4096; i += 256) wb[(i >> 6) * 65 + (i & 63)] = lo1[i];
  __syncthreads();
#pragma unroll
  for (int j = 0; j < 8; ++j) acc[j] = 0.f;
  for (int k = 0; k < 64; ++k) {
    float wv = wb[oc * 65 + k];
#pragma unroll
    for (int j = 0; j < 8; ++j) acc[j] += fst[rb + 4 * j][k] * wv;
  }
#pragma unroll
  for (int j = 0; j < 8; ++j) tmp[rb + 4 * j][oc] = acc[j];
  __syncthreads();

  // comb[:, 64:128] = tmp @ lo2^T
  for (int i = t; i < 4096; i += 256) wb[(i >> 6) * 65 + (i & 63)] = lo2[i];
  __syncthreads();
#pragma unroll
  for (int j = 0; j < 8; ++j) acc[j] = 0.f;
  for (int k = 0; k < 64; ++k) {
    float wv = wb[oc * 65 + k];
#pragma unroll
    for (int j = 0; j < 8; ++j) acc[j] += tmp[rb + 4 * j][k] * wv;
  }
#pragma unroll
  for (int j = 0; j < 8; ++j) comb[rb + 4 * j][64 + oc] = acc[j];
  __syncthreads();

  // last: out = relu(comb @ lastw^T), 4 chunks of 32 output cols
  int oc2 = t & 31, rb2 = t >> 5;
  float accL[4];
  for (int ch = 0; ch < 4; ++ch) {
    for (int i = t; i < 4096; i += 256)
      wb[(i >> 7) * 129 + (i & 127)] = lastw[ch * 4096 + i];
    __syncthreads();
#pragma unroll
    for (int j = 0; j < 4; ++j) accL[j] = 0.f;
    for (int k = 0; k < 128; ++k) {
      float wv = wb[oc2 * 129 + k];
#pragma unroll
      for (int j = 0; j < 4; ++j) accL[j] += comb[rb2 + 8 * j][k] * wv;
    }
#pragma unroll
    for (int j = 0; j < 4; ++j) {
      int r = rb2 + 8 * j;
      int b = r & 3, n = n0 + (r >> 2);
      float v = accL[j];
      out[((size_t)b * NODES + n) * 128 + ch * 32 + oc2] = v > 0.f ? v : 0.f;
    }
    __syncthreads();
  }
}

extern "C" void kernel_launch(void* const* d_in, const int* in_sizes, int n_in,
                              void* d_out, int out_size, void* d_ws, size_t ws_size,
                              hipStream_t stream) {
  const float* x     = (const float*)d_in[0];
  const int*   ei    = (const int*)d_in[1];   // jax default: int64 downcast to int32
  const float* lin_w = (const float*)d_in[2];
  const float* bias  = (const float*)d_in[3];
  const float* up1   = (const float*)d_in[4];
  const float* up2   = (const float*)d_in[5];
  const float* lo1   = (const float*)d_in[6];
  const float* lo2   = (const float*)d_in[7];
  const float* lastw = (const float*)d_in[8];
  float* out = (float*)d_out;

  char* ws = (char*)d_ws;
  float* deg = (float*)ws;                                        // N floats -> becomes dis
  float* hs  = (float*)(ws + (1 << 20));                          // N*256 floats
  float* agg = (float*)(ws + (1 << 20) + (size_t)NODES * 256 * 4);// N*256 floats

  k_deg_init<<<(NODES + 255) / 256, 256, 0, stream>>>(deg);
  k_deg_acc<<<(NEDGE + 255) / 256, 256, 0, stream>>>(ei, deg);
  k_dis<<<(NODES + 255) / 256, 256, 0, stream>>>(deg);
  k_lin<<<NODES / 8, 256, 0, stream>>>(x, lin_w, deg, hs, agg);
  k_scatter<<<(NEDGE * 64) / 256, 256, 0, stream>>>(ei, hs, agg);
  k_post<<<NODES / 8, 256, 0, stream>>>(agg, deg, bias, up1, up2, lo1, lo2, lastw, out);
}

// Round 2
// 509.636 us; speedup vs baseline: 2.8436x; 2.8436x over previous
//
#include <hip/hip_runtime.h>
#include <cstdint>
#include <cstddef>

#define NODES 20000
#define NEDGE 320000

// ---------------- CSR build ----------------

__global__ void k_zero(int* __restrict__ cnt) {
  int i = blockIdx.x * blockDim.x + threadIdx.x;
  if (i < NODES) cnt[i] = 0;
}

__global__ void k_hist(const int* __restrict__ ei, int* __restrict__ cnt) {
  int i = blockIdx.x * blockDim.x + threadIdx.x;
  if (i < NEDGE) atomicAdd(&cnt[ei[NEDGE + i]], 1);  // col = targets
}

// single-block exclusive scan of cnt[0..N) -> rowptr, fill; also dis = rsqrt(cnt+1)
__global__ void k_scan(const int* __restrict__ cnt, int* __restrict__ rowptr,
                       int* __restrict__ fill, float* __restrict__ dis) {
  __shared__ int partial[256];
  __shared__ int offs[257];
  int t = threadIdx.x;
  const int CH = (NODES + 255) / 256;  // 79
  int base = t * CH;
  int s = 0;
  for (int i = 0; i < CH; ++i) {
    int idx = base + i;
    if (idx < NODES) s += cnt[idx];
  }
  partial[t] = s;
  __syncthreads();
  if (t == 0) {
    int acc = 0;
    for (int i = 0; i < 256; ++i) { offs[i] = acc; acc += partial[i]; }
    offs[256] = acc;
  }
  __syncthreads();
  int run = offs[t];
  for (int i = 0; i < CH; ++i) {
    int idx = base + i;
    if (idx < NODES) {
      rowptr[idx] = run;
      fill[idx] = run;
      dis[idx] = rsqrtf((float)(cnt[idx] + 1));  // +1 = self loop
      run += cnt[idx];
    }
  }
  if (t == 255) rowptr[NODES] = offs[256];
}

__global__ void k_fill(const int* __restrict__ ei, int* __restrict__ fill,
                       int* __restrict__ csr_src) {
  int i = blockIdx.x * blockDim.x + threadIdx.x;
  if (i < NEDGE) {
    int row = ei[i];
    int col = ei[NEDGE + i];
    int pos = atomicAdd(&fill[col], 1);
    csr_src[pos] = row;
  }
}

// ---------------- linear + pre-scale by dis[n] ----------------
// hs[n][b][c] = dis[n] * sum_k x[b][n][k] * lin_w[c][k]
__global__ void k_lin(const float* __restrict__ x, const float* __restrict__ lin_w,
                      const float* __restrict__ dis, float* __restrict__ hs) {
  __shared__ float xs[32][65];
  __shared__ float ws[64][65];
  int t = threadIdx.x;
  int n0 = blockIdx.x * 8;
  for (int i = t; i < 64 * 64; i += 256) ws[i >> 6][i & 63] = lin_w[i];
  for (int i = t; i < 32 * 64; i += 256) {
    int r = i >> 6, k = i & 63;
    int b = r & 3, n = n0 + (r >> 2);
    xs[r][k] = x[((size_t)b * NODES + n) * 64 + k];
  }
  __syncthreads();
  int oc = t & 63, rb = t >> 6;
  float acc[8];
#pragma unroll
  for (int j = 0; j < 8; ++j) acc[j] = 0.f;
  for (int k = 0; k < 64; ++k) {
    float wv = ws[oc][k];
#pragma unroll
    for (int j = 0; j < 8; ++j) acc[j] += xs[rb + 4 * j][k] * wv;
  }
#pragma unroll
  for (int j = 0; j < 8; ++j) {
    int r = rb + 4 * j;  // row r <-> (n = n0 + (r>>2), b = r&3)
    int n = n0 + (r >> 2);
    size_t o = ((size_t)(n0 * 4) + r) * 64 + oc;  // (n*4+b)*64 + oc
    hs[o] = acc[j] * dis[n];
  }
}

// ---------------- gather: one wave per node, lane = float4 of 256 channels ----------------
__global__ void k_gather(const int* __restrict__ rowptr, const int* __restrict__ csr_src,
                         const float4* __restrict__ hs4, float4* __restrict__ agg4) {
  int w = (blockIdx.x * blockDim.x + threadIdx.x) >> 6;
  int lane = threadIdx.x & 63;
  if (w >= NODES) return;
  int beg = rowptr[w];
  int end = rowptr[w + 1];
  float4 acc = hs4[(size_t)w * 64 + lane];  // self loop
  int i = beg;
  for (; i + 4 <= end; i += 4) {
    int r0 = csr_src[i], r1 = csr_src[i + 1], r2 = csr_src[i + 2], r3 = csr_src[i + 3];
    float4 a0 = hs4[(size_t)r0 * 64 + lane];
    float4 a1 = hs4[(size_t)r1 * 64 + lane];
    float4 a2 = hs4[(size_t)r2 * 64 + lane];
    float4 a3 = hs4[(size_t)r3 * 64 + lane];
    acc.x += a0.x; acc.y += a0.y; acc.z += a0.z; acc.w += a0.w;
    acc.x += a1.x; acc.y += a1.y; acc.z += a1.z; acc.w += a1.w;
    acc.x += a2.x; acc.y += a2.y; acc.z += a2.z; acc.w += a2.w;
    acc.x += a3.x; acc.y += a3.y; acc.z += a3.z; acc.w += a3.w;
  }
  for (; i < end; ++i) {
    int r = csr_src[i];
    float4 a = hs4[(size_t)r * 64 + lane];
    acc.x += a.x; acc.y += a.y; acc.z += a.z; acc.w += a.w;
  }
  agg4[(size_t)w * 64 + lane] = acc;
}

// ---------------- sigmoid + matmul chain + concat + last + relu ----------------
// per block: 8 nodes -> 32 rows (r = n_local*4 + b) of C=64
__global__ void k_post(const float* __restrict__ agg, const float* __restrict__ dis,
                       const float* __restrict__ bias,
                       const float* __restrict__ up1, const float* __restrict__ up2,
                       const float* __restrict__ lo1, const float* __restrict__ lo2,
                       const float* __restrict__ lastw, float* __restrict__ out) {
  __shared__ float fst[32][65];
  __shared__ float tmp[32][65];
  __shared__ float comb[32][129];
  __shared__ float wb[4160];  // 64x65 (64-wide stages) or 32x129 (last chunks)
  int t = threadIdx.x;
  int n0 = blockIdx.x * 8;

  // fst = sigmoid(agg * dis + bias); agg tile is contiguous [n0*256 .. +2048)
  for (int i = t; i < 32 * 64; i += 256) {
    int r = i >> 6, k = i & 63;
    int n = n0 + (r >> 2);
    float v = agg[(size_t)n0 * 256 + i] * dis[n] + bias[k];
    fst[r][k] = 1.f / (1.f + __expf(-v));
  }
  for (int i = t; i < 4096; i += 256) wb[(i >> 6) * 65 + (i & 63)] = up1[i];
  __syncthreads();

  int oc = t & 63, rb = t >> 6;
  float acc[8];

  // tmp = fst @ up1^T
#pragma unroll
  for (int j = 0; j < 8; ++j) acc[j] = 0.f;
  for (int k = 0; k < 64; ++k) {
    float wv = wb[oc * 65 + k];
#pragma unroll
    for (int j = 0; j < 8; ++j) acc[j] += fst[rb + 4 * j][k] * wv;
  }
#pragma unroll
  for (int j = 0; j < 8; ++j) tmp[rb + 4 * j][oc] = acc[j];
  __syncthreads();

  // comb[:, 0:64] = tmp @ up2^T
  for (int i = t; i < 4096; i += 256) wb[(i >> 6) * 65 + (i & 63)] = up2[i];
  __syncthreads();
#pragma unroll
  for (int j = 0; j < 8; ++j) acc[j] = 0.f;
  for (int k = 0; k < 64; ++k) {
    float wv = wb[oc * 65 + k];
#pragma unroll
    for (int j = 0; j < 8; ++j) acc[j] += tmp[rb + 4 * j][k] * wv;
  }
#pragma unroll
  for (int j = 0; j < 8; ++j) comb[rb + 4 * j][oc] = acc[j];
  __syncthreads();

  // tmp = fst @ lo1^T
  for (int i = t; i < 4096; i += 256) wb[(i >> 6) * 65 + (i & 63)] = lo1[i];
  __syncthreads();
#pragma unroll
  for (int j = 0; j < 8; ++j) acc[j] = 0.f;
  for (int k = 0; k < 64; ++k) {
    float wv = wb[oc * 65 + k];
#pragma unroll
    for (int j = 0; j < 8; ++j) acc[j] += fst[rb + 4 * j][k] * wv;
  }
#pragma unroll
  for (int j = 0; j < 8; ++j) tmp[rb + 4 * j][oc] = acc[j];
  __syncthreads();

  // comb[:, 64:128] = tmp @ lo2^T
  for (int i = t; i < 4096; i += 256) wb[(i >> 6) * 65 + (i & 63)] = lo2[i];
  __syncthreads();
#pragma unroll
  for (int j = 0; j < 8; ++j) acc[j] = 0.f;
  for (int k = 0; k < 64; ++k) {
    float wv = wb[oc * 65 + k];
#pragma unroll
    for (int j = 0; j < 8; ++j) acc[j] += tmp[rb + 4 * j][k] * wv;
  }
#pragma unroll
  for (int j = 0; j < 8; ++j) comb[rb + 4 * j][64 + oc] = acc[j];
  __syncthreads();

  // last: out = relu(comb @ lastw^T), 4 chunks of 32 output cols
  int oc2 = t & 31, rb2 = t >> 5;
  float accL[4];
  for (int ch = 0; ch < 4; ++ch) {
    for (int i = t; i < 4096; i += 256)
      wb[(i >> 7) * 129 + (i & 127)] = lastw[ch * 4096 + i];
    __syncthreads();
#pragma unroll
    for (int j = 0; j < 4; ++j) accL[j] = 0.f;
    for (int k = 0; k < 128; ++k) {
      float wv = wb[oc2 * 129 + k];
#pragma unroll
      for (int j = 0; j < 4; ++j) accL[j] += comb[rb2 + 8 * j][k] * wv;
    }
#pragma unroll
    for (int j = 0; j < 4; ++j) {
      int r = rb2 + 8 * j;
      int b = r & 3, n = n0 + (r >> 2);
      float v = accL[j];
      out[((size_t)b * NODES + n) * 128 + ch * 32 + oc2] = v > 0.f ? v : 0.f;
    }
    __syncthreads();
  }
}

extern "C" void kernel_launch(void* const* d_in, const int* in_sizes, int n_in,
                              void* d_out, int out_size, void* d_ws, size_t ws_size,
                              hipStream_t stream) {
  const float* x     = (const float*)d_in[0];
  const int*   ei    = (const int*)d_in[1];   // jax default: int64 -> int32 buffer
  const float* lin_w = (const float*)d_in[2];
  const float* bias  = (const float*)d_in[3];
  const float* up1   = (const float*)d_in[4];
  const float* up2   = (const float*)d_in[5];
  const float* lo1   = (const float*)d_in[6];
  const float* lo2   = (const float*)d_in[7];
  const float* lastw = (const float*)d_in[8];
  float* out = (float*)d_out;

  char* ws = (char*)d_ws;
  float* dis     = (float*)(ws);                 // N f32
  int*   cnt     = (int*)(ws + (128 << 10));     // N i32
  int*   rowptr  = (int*)(ws + (256 << 10));     // N+1 i32
  int*   fill    = (int*)(ws + (384 << 10));     // N i32
  int*   csr_src = (int*)(ws + (512 << 10));     // E i32 (1.28 MB)
  float* hs      = (float*)(ws + (2 << 20));                               // N*256 f32
  float* agg     = (float*)(ws + (2 << 20) + (size_t)NODES * 256 * 4);     // N*256 f32

  k_zero<<<(NODES + 255) / 256, 256, 0, stream>>>(cnt);
  k_hist<<<(NEDGE + 255) / 256, 256, 0, stream>>>(ei, cnt);
  k_scan<<<1, 256, 0, stream>>>(cnt, rowptr, fill, dis);
  k_fill<<<(NEDGE + 255) / 256, 256, 0, stream>>>(ei, fill, csr_src);
  k_lin<<<NODES / 8, 256, 0, stream>>>(x, lin_w, dis, hs);
  k_gather<<<(NODES * 64 + 255) / 256, 256, 0, stream>>>(rowptr, csr_src,
                                                         (const float4*)hs, (float4*)agg);
  k_post<<<NODES / 8, 256, 0, stream>>>(agg, dis, bias, up1, up2, lo1, lo2, lastw, out);
}

// Round 3
// 269.951 us; speedup vs baseline: 5.3684x; 1.8879x over previous
//
#include <hip/hip_runtime.h>
#include <cstdint>
#include <cstddef>

#define NODES 20000
#define NEDGE 320000

using bf16x8 = __attribute__((ext_vector_type(8))) __bf16;
using f32x4  = __attribute__((ext_vector_type(4))) float;

__device__ __forceinline__ unsigned short f2bf(float f) {
  union { float f; unsigned int u; } v; v.f = f;
  unsigned int r = v.u + 0x7FFF + ((v.u >> 16) & 1);  // RNE
  return (unsigned short)(r >> 16);
}
__device__ __forceinline__ float bf2f(unsigned short u) {
  union { unsigned int u; float f; } v; v.u = ((unsigned int)u) << 16;
  return v.f;
}

// ---------------- CSR build ----------------

__global__ void k_zero(int* __restrict__ cnt) {
  int i = blockIdx.x * blockDim.x + threadIdx.x;
  if (i < NODES) cnt[i] = 0;
}

__global__ void k_hist(const int* __restrict__ ei, int* __restrict__ cnt) {
  int i = blockIdx.x * blockDim.x + threadIdx.x;
  if (i < NEDGE) atomicAdd(&cnt[ei[NEDGE + i]], 1);  // col = targets
}

__global__ void k_scan(const int* __restrict__ cnt, int* __restrict__ rowptr,
                       int* __restrict__ fill, float* __restrict__ dis) {
  __shared__ int partial[256];
  __shared__ int offs[257];
  int t = threadIdx.x;
  const int CH = (NODES + 255) / 256;  // 79
  int base = t * CH;
  int s = 0;
  for (int i = 0; i < CH; ++i) {
    int idx = base + i;
    if (idx < NODES) s += cnt[idx];
  }
  partial[t] = s;
  __syncthreads();
  if (t == 0) {
    int acc = 0;
    for (int i = 0; i < 256; ++i) { offs[i] = acc; acc += partial[i]; }
    offs[256] = acc;
  }
  __syncthreads();
  int run = offs[t];
  for (int i = 0; i < CH; ++i) {
    int idx = base + i;
    if (idx < NODES) {
      rowptr[idx] = run;
      fill[idx] = run;
      dis[idx] = rsqrtf((float)(cnt[idx] + 1));  // +1 = self loop
      run += cnt[idx];
    }
  }
  if (t == 255) rowptr[NODES] = offs[256];
}

__global__ void k_fill(const int* __restrict__ ei, int* __restrict__ fill,
                       int* __restrict__ csr_src) {
  int i = blockIdx.x * blockDim.x + threadIdx.x;
  if (i < NEDGE) {
    int row = ei[i];
    int col = ei[NEDGE + i];
    int pos = atomicAdd(&fill[col], 1);
    csr_src[pos] = row;
  }
}

// ---------------- weight fp32 -> bf16 pre-convert ----------------
// dst layout (bf16 elems): [0)lin [4096)up1 [8192)up2 [12288)lo1 [16384)lo2 [20480..36864)last
__global__ void k_wconv(const float* __restrict__ lin, const float* __restrict__ u1,
                        const float* __restrict__ u2, const float* __restrict__ l1,
                        const float* __restrict__ l2, const float* __restrict__ lw,
                        unsigned short* __restrict__ dst) {
  int i = blockIdx.x * blockDim.x + threadIdx.x;
  if (i >= 36864) return;
  float s;
  if (i < 4096) s = lin[i];
  else if (i < 8192) s = u1[i - 4096];
  else if (i < 12288) s = u2[i - 8192];
  else if (i < 16384) s = l1[i - 12288];
  else if (i < 20480) s = l2[i - 16384];
  else s = lw[i - 20480];
  dst[i] = f2bf(s);
}

// ---------------- k_lin: MFMA, hs[n][b][c] = dis[n] * (x @ lin_w^T), bf16 out ----------------
// block = 16 nodes -> 64 rows (r = nl*4 + b); 4 waves
__global__ __launch_bounds__(256) void k_lin(const float* __restrict__ x,
                                             const unsigned short* __restrict__ wlin,
                                             const float* __restrict__ dis,
                                             unsigned short* __restrict__ hs) {
  __shared__ unsigned short xs[64][72];
  int t = threadIdx.x;
  int n0 = blockIdx.x * 16;
  for (int i = t; i < 1024; i += 256) {
    int row = i >> 4, kq = i & 15;
    int n = n0 + (row >> 2), b = row & 3;
    float4 v = *(const float4*)(x + ((size_t)b * NODES + n) * 64 + kq * 4);
    ushort4 o;
    o.x = f2bf(v.x); o.y = f2bf(v.y); o.z = f2bf(v.z); o.w = f2bf(v.w);
    *(ushort4*)&xs[row][kq * 4] = o;
  }
  __syncthreads();
  int w = t >> 6, l = t & 63, m = l & 15, q = l >> 4;
  f32x4 acc[4] = {{0,0,0,0},{0,0,0,0},{0,0,0,0},{0,0,0,0}};
#pragma unroll
  for (int kk = 0; kk < 2; ++kk) {
    bf16x8 a = *(const bf16x8*)&xs[16 * w + m][q * 8 + 32 * kk];
#pragma unroll
    for (int ct = 0; ct < 4; ++ct) {
      bf16x8 bfr = *(const bf16x8*)(wlin + (ct * 16 + m) * 64 + q * 8 + 32 * kk);
      acc[ct] = __builtin_amdgcn_mfma_f32_16x16x32_bf16(a, bfr, acc[ct], 0, 0, 0);
    }
  }
  float ds = dis[n0 + 4 * w + q];  // node for D rows of this (wave,quad)
#pragma unroll
  for (int ct = 0; ct < 4; ++ct)
#pragma unroll
    for (int r = 0; r < 4; ++r) {
      int rblk = 16 * w + 4 * q + r;
      hs[((size_t)(n0 * 4) + rblk) * 64 + ct * 16 + m] = f2bf(acc[ct][r] * ds);
    }
}

// ---------------- gather: one wave per node, lane = 4 bf16 channels ----------------
__global__ __launch_bounds__(256) void k_gather(const int* __restrict__ rowptr,
                                                const int* __restrict__ csr_src,
                                                const unsigned short* __restrict__ hs,
                                                unsigned short* __restrict__ agg) {
  int wid = (blockIdx.x * blockDim.x + threadIdx.x) >> 6;
  int lane = threadIdx.x & 63;
  if (wid >= NODES) return;
  int beg = rowptr[wid], end = rowptr[wid + 1];
  int off = lane * 4;
  ushort4 s = *(const ushort4*)(hs + (size_t)wid * 256 + off);  // self loop
  float a0 = bf2f(s.x), a1 = bf2f(s.y), a2 = bf2f(s.z), a3 = bf2f(s.w);
  int i = beg;
  for (; i + 4 <= end; i += 4) {
    int r0 = csr_src[i], r1 = csr_src[i + 1], r2 = csr_src[i + 2], r3 = csr_src[i + 3];
    ushort4 v0 = *(const ushort4*)(hs + (size_t)r0 * 256 + off);
    ushort4 v1 = *(const ushort4*)(hs + (size_t)r1 * 256 + off);
    ushort4 v2 = *(const ushort4*)(hs + (size_t)r2 * 256 + off);
    ushort4 v3 = *(const ushort4*)(hs + (size_t)r3 * 256 + off);
    a0 += bf2f(v0.x) + bf2f(v1.x) + bf2f(v2.x) + bf2f(v3.x);
    a1 += bf2f(v0.y) + bf2f(v1.y) + bf2f(v2.y) + bf2f(v3.y);
    a2 += bf2f(v0.z) + bf2f(v1.z) + bf2f(v2.z) + bf2f(v3.z);
    a3 += bf2f(v0.w) + bf2f(v1.w) + bf2f(v2.w) + bf2f(v3.w);
  }
  for (; i < end; ++i) {
    int r = csr_src[i];
    ushort4 v = *(const ushort4*)(hs + (size_t)r * 256 + off);
    a0 += bf2f(v.x); a1 += bf2f(v.y); a2 += bf2f(v.z); a3 += bf2f(v.w);
  }
  ushort4 o;
  o.x = f2bf(a0); o.y = f2bf(a1); o.z = f2bf(a2); o.w = f2bf(a3);
  *(ushort4*)(agg + (size_t)wid * 256 + off) = o;
}

// ---------------- k_post: sigmoid + MFMA chain + last + relu ----------------
// per block: 16 nodes -> 64 rows; stage helper computes dst[0:64) = src @ W^T (bf16)
template <int DS>
__device__ __forceinline__ void mm64_stage(const unsigned short (*src)[72],
                                           const unsigned short* __restrict__ wgt,
                                           unsigned short (*dst)[DS], int dcol0, int t) {
  int w = t >> 6, l = t & 63, m = l & 15, q = l >> 4;
  f32x4 acc[4] = {{0,0,0,0},{0,0,0,0},{0,0,0,0},{0,0,0,0}};
#pragma unroll
  for (int kk = 0; kk < 2; ++kk) {
    bf16x8 a = *(const bf16x8*)&src[16 * w + m][q * 8 + 32 * kk];
#pragma unroll
    for (int ct = 0; ct < 4; ++ct) {
      bf16x8 b = *(const bf16x8*)(wgt + (ct * 16 + m) * 64 + q * 8 + 32 * kk);
      acc[ct] = __builtin_amdgcn_mfma_f32_16x16x32_bf16(a, b, acc[ct], 0, 0, 0);
    }
  }
#pragma unroll
  for (int ct = 0; ct < 4; ++ct)
#pragma unroll
    for (int r = 0; r < 4; ++r)
      dst[16 * w + 4 * q + r][dcol0 + ct * 16 + m] = f2bf(acc[ct][r]);
}

__global__ __launch_bounds__(256) void k_post(const unsigned short* __restrict__ agg,
                                              const float* __restrict__ dis,
                                              const float* __restrict__ bias,
                                              const unsigned short* __restrict__ wb,
                                              float* __restrict__ out) {
  __shared__ unsigned short fst_s[64][72];
  __shared__ unsigned short tmp_s[64][72];
  __shared__ unsigned short comb_s[64][136];
  int t = threadIdx.x;
  int n0 = blockIdx.x * 16;

  // stage 0: fst = sigmoid(agg * dis + bias)
  {
    float4 b4 = *(const float4*)(bias + (t & 15) * 4);
    for (int i = t; i < 1024; i += 256) {
      int row = i >> 4, k4 = (i & 15) * 4;
      int n = n0 + (row >> 2);
      float ds = dis[n];
      ushort4 u = *(const ushort4*)(agg + (size_t)n0 * 256 + i * 4);
      float v0 = bf2f(u.x) * ds + b4.x;
      float v1 = bf2f(u.y) * ds + b4.y;
      float v2 = bf2f(u.z) * ds + b4.z;
      float v3 = bf2f(u.w) * ds + b4.w;
      ushort4 o;
      o.x = f2bf(1.f / (1.f + __expf(-v0)));
      o.y = f2bf(1.f / (1.f + __expf(-v1)));
      o.z = f2bf(1.f / (1.f + __expf(-v2)));
      o.w = f2bf(1.f / (1.f + __expf(-v3)));
      *(ushort4*)&fst_s[row][k4] = o;
    }
  }
  __syncthreads();
  mm64_stage<72>(fst_s, wb + 4096, tmp_s, 0, t);     // t_up = fst @ up1^T
  __syncthreads();
  mm64_stage<136>(tmp_s, wb + 8192, comb_s, 0, t);   // upper = t_up @ up2^T
  __syncthreads();
  mm64_stage<72>(fst_s, wb + 12288, tmp_s, 0, t);    // t_lo = fst @ lo1^T
  __syncthreads();
  mm64_stage<136>(tmp_s, wb + 16384, comb_s, 64, t); // lower = t_lo @ lo2^T
  __syncthreads();

  // stage E: out = relu(comb @ last^T), K=128, 128 output cols
  {
    const unsigned short* wlast = wb + 20480;
    int w = t >> 6, l = t & 63, m = l & 15, q = l >> 4;
    f32x4 acc[8] = {{0,0,0,0},{0,0,0,0},{0,0,0,0},{0,0,0,0},
                    {0,0,0,0},{0,0,0,0},{0,0,0,0},{0,0,0,0}};
#pragma unroll
    for (int kk = 0; kk < 4; ++kk) {
      bf16x8 a = *(const bf16x8*)&comb_s[16 * w + m][q * 8 + 32 * kk];
#pragma unroll
      for (int ct = 0; ct < 8; ++ct) {
        bf16x8 b = *(const bf16x8*)(wlast + (ct * 16 + m) * 128 + q * 8 + 32 * kk);
        acc[ct] = __builtin_amdgcn_mfma_f32_16x16x32_bf16(a, b, acc[ct], 0, 0, 0);
      }
    }
    int n = n0 + 4 * w + q;  // D rows 16w+4q+r -> node n, batch b=r
#pragma unroll
    for (int ct = 0; ct < 8; ++ct)
#pragma unroll
      for (int r = 0; r < 4; ++r) {
        float v = acc[ct][r];
        out[((size_t)r * NODES + n) * 128 + ct * 16 + m] = v > 0.f ? v : 0.f;
      }
  }
}

extern "C" void kernel_launch(void* const* d_in, const int* in_sizes, int n_in,
                              void* d_out, int out_size, void* d_ws, size_t ws_size,
                              hipStream_t stream) {
  const float* x     = (const float*)d_in[0];
  const int*   ei    = (const int*)d_in[1];
  const float* lin_w = (const float*)d_in[2];
  const float* bias  = (const float*)d_in[3];
  const float* up1   = (const float*)d_in[4];
  const float* up2   = (const float*)d_in[5];
  const float* lo1   = (const float*)d_in[6];
  const float* lo2   = (const float*)d_in[7];
  const float* lastw = (const float*)d_in[8];
  float* out = (float*)d_out;

  char* ws = (char*)d_ws;
  unsigned short* wb16 = (unsigned short*)(ws);            // 73728 B
  float* dis     = (float*)(ws + (128 << 10));
  int*   cnt     = (int*)(ws + (256 << 10));
  int*   rowptr  = (int*)(ws + (384 << 10));
  int*   fill    = (int*)(ws + (512 << 10));
  int*   csr_src = (int*)(ws + (1 << 20));                 // 1.28 MB
  unsigned short* hs  = (unsigned short*)(ws + (4 << 20)); // 10.24 MB
  unsigned short* agg = (unsigned short*)(ws + (16 << 20));// 10.24 MB

  k_zero<<<(NODES + 255) / 256, 256, 0, stream>>>(cnt);
  k_hist<<<(NEDGE + 255) / 256, 256, 0, stream>>>(ei, cnt);
  k_wconv<<<144, 256, 0, stream>>>(lin_w, up1, up2, lo1, lo2, lastw, wb16);
  k_scan<<<1, 256, 0, stream>>>(cnt, rowptr, fill, dis);
  k_fill<<<(NEDGE + 255) / 256, 256, 0, stream>>>(ei, fill, csr_src);
  k_lin<<<NODES / 16, 256, 0, stream>>>(x, wb16, dis, hs);
  k_gather<<<(NODES * 64 + 255) / 256, 256, 0, stream>>>(rowptr, csr_src, hs, agg);
  k_post<<<NODES / 16, 256, 0, stream>>>(agg, dis, bias, wb16, out);
}

// Round 4
// 209.277 us; speedup vs baseline: 6.9248x; 1.2899x over previous
//
#include <hip/hip_runtime.h>
#include <cstdint>
#include <cstddef>

#define NODES 20000
#define NEDGE 320000
#define NB 79  // ceil(NODES/256)

using bf16x8 = __attribute__((ext_vector_type(8))) __bf16;
using f32x4  = __attribute__((ext_vector_type(4))) float;

__device__ __forceinline__ unsigned short f2bf(float f) {
  union { float f; unsigned int u; } v; v.f = f;
  unsigned int r = v.u + 0x7FFF + ((v.u >> 16) & 1);  // RNE
  return (unsigned short)(r >> 16);
}
__device__ __forceinline__ float bf2f(unsigned short u) {
  union { unsigned int u; float f; } v; v.u = ((unsigned int)u) << 16;
  return v.f;
}

// ---------------- prep: zero cnt + weight fp32->bf16 convert (fused) ----------------
// wb16 layout (bf16 elems): [0)lin [4096)up1 [8192)up2 [12288)lo1 [16384)lo2 [20480..36864)last
__global__ void k_prep(const float* __restrict__ lin, const float* __restrict__ u1,
                       const float* __restrict__ u2, const float* __restrict__ l1,
                       const float* __restrict__ l2, const float* __restrict__ lw,
                       unsigned short* __restrict__ dst, int* __restrict__ cnt) {
  int g = blockIdx.x * blockDim.x + threadIdx.x;
  if (g < 36864) {
    float s;
    if (g < 4096) s = lin[g];
    else if (g < 8192) s = u1[g - 4096];
    else if (g < 12288) s = u2[g - 8192];
    else if (g < 16384) s = l1[g - 12288];
    else if (g < 20480) s = l2[g - 16384];
    else s = lw[g - 20480];
    dst[g] = f2bf(s);
  } else {
    int z = g - 36864;
    if (z < NODES) cnt[z] = 0;
  }
}

__global__ void k_hist(const int* __restrict__ ei, int* __restrict__ cnt) {
  int i = blockIdx.x * blockDim.x + threadIdx.x;
  if (i < NEDGE) atomicAdd(&cnt[ei[NEDGE + i]], 1);  // col = targets
}

// ---------------- 3-phase parallel scan ----------------

__global__ void k_bsum(const int* __restrict__ cnt, int* __restrict__ bsum,
                       float* __restrict__ dis) {
  int t = threadIdx.x;
  int idx = blockIdx.x * 256 + t;
  int v = (idx < NODES) ? cnt[idx] : 0;
  if (idx < NODES) dis[idx] = rsqrtf((float)(v + 1));  // +1 = self loop
  int s = v;
#pragma unroll
  for (int d = 1; d < 64; d <<= 1) s += __shfl_down(s, d, 64);
  __shared__ int wsum[4];
  if ((t & 63) == 0) wsum[t >> 6] = s;
  __syncthreads();
  if (t == 0) bsum[blockIdx.x] = wsum[0] + wsum[1] + wsum[2] + wsum[3];
}

__global__ void k_bscan(const int* __restrict__ bsum, int* __restrict__ boff) {
  int t = threadIdx.x;  // 128
  int lane = t & 63, w = t >> 6;
  int v = (t < NB) ? bsum[t] : 0;
  int inc = v;
#pragma unroll
  for (int d = 1; d < 64; d <<= 1) {
    int n = __shfl_up(inc, d, 64);
    if (lane >= d) inc += n;
  }
  __shared__ int ws0;
  if (w == 0 && lane == 63) ws0 = inc;
  __syncthreads();
  int off = (w == 1) ? ws0 : 0;
  if (t < NB) boff[t] = off + inc - v;
}

__global__ void k_rowptr(const int* __restrict__ cnt, const int* __restrict__ boff,
                         int* __restrict__ rowptr, int* __restrict__ fill) {
  int t = threadIdx.x;
  int idx = blockIdx.x * 256 + t;
  int v = (idx < NODES) ? cnt[idx] : 0;
  int lane = t & 63, w = t >> 6;
  int inc = v;
#pragma unroll
  for (int d = 1; d < 64; d <<= 1) {
    int n = __shfl_up(inc, d, 64);
    if (lane >= d) inc += n;
  }
  __shared__ int wsum[4];
  if (lane == 63) wsum[w] = inc;
  __syncthreads();
  int wo = 0;
#pragma unroll
  for (int i = 0; i < 4; ++i)
    if (i < w) wo += wsum[i];
  int r = boff[blockIdx.x] + wo + inc - v;
  if (idx < NODES) {
    rowptr[idx] = r;
    fill[idx] = r;
    if (idx == NODES - 1) rowptr[NODES] = r + v;
  }
}

__global__ void k_fill(const int* __restrict__ ei, int* __restrict__ fill,
                       int* __restrict__ csr_src) {
  int i = blockIdx.x * blockDim.x + threadIdx.x;
  if (i < NEDGE) {
    int row = ei[i];
    int col = ei[NEDGE + i];
    int pos = atomicAdd(&fill[col], 1);
    csr_src[pos] = row;
  }
}

// ---------------- k_lin: MFMA, hs[n][b][c] = dis[n] * (x @ lin_w^T), bf16 out ----------------
__global__ __launch_bounds__(256) void k_lin(const float* __restrict__ x,
                                             const unsigned short* __restrict__ wlin,
                                             const float* __restrict__ dis,
                                             unsigned short* __restrict__ hs) {
  __shared__ unsigned short xs[64][72];
  int t = threadIdx.x;
  int n0 = blockIdx.x * 16;
  for (int i = t; i < 1024; i += 256) {
    int row = i >> 4, kq = i & 15;
    int n = n0 + (row >> 2), b = row & 3;
    float4 v = *(const float4*)(x + ((size_t)b * NODES + n) * 64 + kq * 4);
    ushort4 o;
    o.x = f2bf(v.x); o.y = f2bf(v.y); o.z = f2bf(v.z); o.w = f2bf(v.w);
    *(ushort4*)&xs[row][kq * 4] = o;
  }
  __syncthreads();
  int w = t >> 6, l = t & 63, m = l & 15, q = l >> 4;
  f32x4 acc[4] = {{0,0,0,0},{0,0,0,0},{0,0,0,0},{0,0,0,0}};
#pragma unroll
  for (int kk = 0; kk < 2; ++kk) {
    bf16x8 a = *(const bf16x8*)&xs[16 * w + m][q * 8 + 32 * kk];
#pragma unroll
    for (int ct = 0; ct < 4; ++ct) {
      bf16x8 bfr = *(const bf16x8*)(wlin + (ct * 16 + m) * 64 + q * 8 + 32 * kk);
      acc[ct] = __builtin_amdgcn_mfma_f32_16x16x32_bf16(a, bfr, acc[ct], 0, 0, 0);
    }
  }
  float ds = dis[n0 + 4 * w + q];
#pragma unroll
  for (int ct = 0; ct < 4; ++ct)
#pragma unroll
    for (int r = 0; r < 4; ++r) {
      int rblk = 16 * w + 4 * q + r;
      hs[((size_t)(n0 * 4) + rblk) * 64 + ct * 16 + m] = f2bf(acc[ct][r] * ds);
    }
}

// ---------------- gather: one wave per node, lane = 4 bf16 channels ----------------
__global__ __launch_bounds__(256) void k_gather(const int* __restrict__ rowptr,
                                                const int* __restrict__ csr_src,
                                                const unsigned short* __restrict__ hs,
                                                unsigned short* __restrict__ agg) {
  int wid = (blockIdx.x * blockDim.x + threadIdx.x) >> 6;
  int lane = threadIdx.x & 63;
  if (wid >= NODES) return;
  int beg = rowptr[wid], end = rowptr[wid + 1];
  int off = lane * 4;
  ushort4 s = *(const ushort4*)(hs + (size_t)wid * 256 + off);  // self loop
  float a0 = bf2f(s.x), a1 = bf2f(s.y), a2 = bf2f(s.z), a3 = bf2f(s.w);
  int i = beg;
  for (; i + 4 <= end; i += 4) {
    int r0 = csr_src[i], r1 = csr_src[i + 1], r2 = csr_src[i + 2], r3 = csr_src[i + 3];
    ushort4 v0 = *(const ushort4*)(hs + (size_t)r0 * 256 + off);
    ushort4 v1 = *(const ushort4*)(hs + (size_t)r1 * 256 + off);
    ushort4 v2 = *(const ushort4*)(hs + (size_t)r2 * 256 + off);
    ushort4 v3 = *(const ushort4*)(hs + (size_t)r3 * 256 + off);
    a0 += bf2f(v0.x) + bf2f(v1.x) + bf2f(v2.x) + bf2f(v3.x);
    a1 += bf2f(v0.y) + bf2f(v1.y) + bf2f(v2.y) + bf2f(v3.y);
    a2 += bf2f(v0.z) + bf2f(v1.z) + bf2f(v2.z) + bf2f(v3.z);
    a3 += bf2f(v0.w) + bf2f(v1.w) + bf2f(v2.w) + bf2f(v3.w);
  }
  for (; i < end; ++i) {
    int r = csr_src[i];
    ushort4 v = *(const ushort4*)(hs + (size_t)r * 256 + off);
    a0 += bf2f(v.x); a1 += bf2f(v.y); a2 += bf2f(v.z); a3 += bf2f(v.w);
  }
  ushort4 o;
  o.x = f2bf(a0); o.y = f2bf(a1); o.z = f2bf(a2); o.w = f2bf(a3);
  *(ushort4*)(agg + (size_t)wid * 256 + off) = o;
}

// ---------------- k_post: sigmoid + MFMA chain + last + relu ----------------
template <int DS>
__device__ __forceinline__ void mm64_stage(const unsigned short (*src)[72],
                                           const unsigned short* __restrict__ wgt,
                                           unsigned short (*dst)[DS], int dcol0, int t) {
  int w = t >> 6, l = t & 63, m = l & 15, q = l >> 4;
  f32x4 acc[4] = {{0,0,0,0},{0,0,0,0},{0,0,0,0},{0,0,0,0}};
#pragma unroll
  for (int kk = 0; kk < 2; ++kk) {
    bf16x8 a = *(const bf16x8*)&src[16 * w + m][q * 8 + 32 * kk];
#pragma unroll
    for (int ct = 0; ct < 4; ++ct) {
      bf16x8 b = *(const bf16x8*)(wgt + (ct * 16 + m) * 64 + q * 8 + 32 * kk);
      acc[ct] = __builtin_amdgcn_mfma_f32_16x16x32_bf16(a, b, acc[ct], 0, 0, 0);
    }
  }
#pragma unroll
  for (int ct = 0; ct < 4; ++ct)
#pragma unroll
    for (int r = 0; r < 4; ++r)
      dst[16 * w + 4 * q + r][dcol0 + ct * 16 + m] = f2bf(acc[ct][r]);
}

__global__ __launch_bounds__(256) void k_post(const unsigned short* __restrict__ agg,
                                              const float* __restrict__ dis,
                                              const float* __restrict__ bias,
                                              const unsigned short* __restrict__ wb,
                                              float* __restrict__ out) {
  __shared__ unsigned short fst_s[64][72];
  __shared__ unsigned short tmp_s[64][72];
  __shared__ unsigned short comb_s[64][136];
  int t = threadIdx.x;
  int n0 = blockIdx.x * 16;

  {
    float4 b4 = *(const float4*)(bias + (t & 15) * 4);
    for (int i = t; i < 1024; i += 256) {
      int row = i >> 4, k4 = (i & 15) * 4;
      int n = n0 + (row >> 2);
      float ds = dis[n];
      ushort4 u = *(const ushort4*)(agg + (size_t)n0 * 256 + i * 4);
      float v0 = bf2f(u.x) * ds + b4.x;
      float v1 = bf2f(u.y) * ds + b4.y;
      float v2 = bf2f(u.z) * ds + b4.z;
      float v3 = bf2f(u.w) * ds + b4.w;
      ushort4 o;
      o.x = f2bf(1.f / (1.f + __expf(-v0)));
      o.y = f2bf(1.f / (1.f + __expf(-v1)));
      o.z = f2bf(1.f / (1.f + __expf(-v2)));
      o.w = f2bf(1.f / (1.f + __expf(-v3)));
      *(ushort4*)&fst_s[row][k4] = o;
    }
  }
  __syncthreads();
  mm64_stage<72>(fst_s, wb + 4096, tmp_s, 0, t);     // t_up = fst @ up1^T
  __syncthreads();
  mm64_stage<136>(tmp_s, wb + 8192, comb_s, 0, t);   // upper = t_up @ up2^T
  __syncthreads();
  mm64_stage<72>(fst_s, wb + 12288, tmp_s, 0, t);    // t_lo = fst @ lo1^T
  __syncthreads();
  mm64_stage<136>(tmp_s, wb + 16384, comb_s, 64, t); // lower = t_lo @ lo2^T
  __syncthreads();

  {
    const unsigned short* wlast = wb + 20480;
    int w = t >> 6, l = t & 63, m = l & 15, q = l >> 4;
    f32x4 acc[8] = {{0,0,0,0},{0,0,0,0},{0,0,0,0},{0,0,0,0},
                    {0,0,0,0},{0,0,0,0},{0,0,0,0},{0,0,0,0}};
#pragma unroll
    for (int kk = 0; kk < 4; ++kk) {
      bf16x8 a = *(const bf16x8*)&comb_s[16 * w + m][q * 8 + 32 * kk];
#pragma unroll
      for (int ct = 0; ct < 8; ++ct) {
        bf16x8 b = *(const bf16x8*)(wlast + (ct * 16 + m) * 128 + q * 8 + 32 * kk);
        acc[ct] = __builtin_amdgcn_mfma_f32_16x16x32_bf16(a, b, acc[ct], 0, 0, 0);
      }
    }
    int n = n0 + 4 * w + q;
#pragma unroll
    for (int ct = 0; ct < 8; ++ct)
#pragma unroll
      for (int r = 0; r < 4; ++r) {
        float v = acc[ct][r];
        out[((size_t)r * NODES + n) * 128 + ct * 16 + m] = v > 0.f ? v : 0.f;
      }
  }
}

extern "C" void kernel_launch(void* const* d_in, const int* in_sizes, int n_in,
                              void* d_out, int out_size, void* d_ws, size_t ws_size,
                              hipStream_t stream) {
  const float* x     = (const float*)d_in[0];
  const int*   ei    = (const int*)d_in[1];
  const float* lin_w = (const float*)d_in[2];
  const float* bias  = (const float*)d_in[3];
  const float* up1   = (const float*)d_in[4];
  const float* up2   = (const float*)d_in[5];
  const float* lo1   = (const float*)d_in[6];
  const float* lo2   = (const float*)d_in[7];
  const float* lastw = (const float*)d_in[8];
  float* out = (float*)d_out;

  char* ws = (char*)d_ws;
  unsigned short* wb16 = (unsigned short*)(ws);            // 73728 B
  float* dis     = (float*)(ws + (128 << 10));
  int*   cnt     = (int*)(ws + (256 << 10));
  int*   rowptr  = (int*)(ws + (384 << 10));
  int*   fill    = (int*)(ws + (512 << 10));
  int*   bsum    = (int*)(ws + (640 << 10));               // NB ints
  int*   boff    = (int*)(ws + (644 << 10));               // NB ints
  int*   csr_src = (int*)(ws + (1 << 20));                 // 1.28 MB
  unsigned short* hs  = (unsigned short*)(ws + (4 << 20)); // 10.24 MB
  unsigned short* agg = (unsigned short*)(ws + (16 << 20));// 10.24 MB

  k_prep<<<(36864 + NODES + 255) / 256, 256, 0, stream>>>(lin_w, up1, up2, lo1, lo2,
                                                          lastw, wb16, cnt);
  k_hist<<<(NEDGE + 255) / 256, 256, 0, stream>>>(ei, cnt);
  k_bsum<<<NB, 256, 0, stream>>>(cnt, bsum, dis);
  k_bscan<<<1, 128, 0, stream>>>(bsum, boff);
  k_rowptr<<<NB, 256, 0, stream>>>(cnt, boff, rowptr, fill);
  k_fill<<<(NEDGE + 255) / 256, 256, 0, stream>>>(ei, fill, csr_src);
  k_lin<<<NODES / 16, 256, 0, stream>>>(x, wb16, dis, hs);
  k_gather<<<(NODES * 64 + 255) / 256, 256, 0, stream>>>(rowptr, csr_src, hs, agg);
  k_post<<<NODES / 16, 256, 0, stream>>>(agg, dis, bias, wb16, out);
}

// Round 5
// 173.482 us; speedup vs baseline: 8.3536x; 1.2063x over previous
//
#include <hip/hip_runtime.h>
#include <cstdint>
#include <cstddef>

#define NODES 20000
#define NEDGE 320000
#define NB 79  // ceil(NODES/256)

using bf16x8 = __attribute__((ext_vector_type(8))) __bf16;
using f32x4  = __attribute__((ext_vector_type(4))) float;

__device__ __forceinline__ unsigned short f2bf(float f) {
  union { float f; unsigned int u; } v; v.f = f;
  unsigned int r = v.u + 0x7FFF + ((v.u >> 16) & 1);  // RNE
  return (unsigned short)(r >> 16);
}
__device__ __forceinline__ float bf2f(unsigned short u) {
  union { unsigned int u; float f; } v; v.u = ((unsigned int)u) << 16;
  return v.f;
}

// ---------------- prep: lin->bf16, M1=up2@up1, M2=lo2@lo1 (fp32), zero cnt ----------------
__global__ void k_prep(const float* __restrict__ lin, const float* __restrict__ u1,
                       const float* __restrict__ u2, const float* __restrict__ l1,
                       const float* __restrict__ l2, unsigned short* __restrict__ wb16,
                       float* __restrict__ M1, float* __restrict__ M2,
                       int* __restrict__ cnt) {
  int g = blockIdx.x * blockDim.x + threadIdx.x;
  if (g < 4096) {
    wb16[g] = f2bf(lin[g]);
  } else if (g < 8192) {
    int id = g - 4096, i = id >> 6, j = id & 63;
    float s = 0.f;
    for (int k = 0; k < 64; ++k) s += u2[i * 64 + k] * u1[k * 64 + j];
    M1[id] = s;
  } else if (g < 12288) {
    int id = g - 8192, i = id >> 6, j = id & 63;
    float s = 0.f;
    for (int k = 0; k < 64; ++k) s += l2[i * 64 + k] * l1[k * 64 + j];
    M2[id] = s;
  } else if (g < 12288 + NODES) {
    cnt[g - 12288] = 0;
  }
}

__global__ void k_hist(const int* __restrict__ ei, int* __restrict__ cnt) {
  int i = blockIdx.x * blockDim.x + threadIdx.x;
  if (i < NEDGE) atomicAdd(&cnt[ei[NEDGE + i]], 1);  // col = targets
}

// ---------------- bsum (+dis) for blocks <79; BigW fold for blocks >=79 ----------------
// BigW[o][j] = sum_k last[o*128+k]*M1[k*64+j] + last[o*128+64+k]*M2[k*64+j]  -> bf16 at wb16+4096
__global__ void k_bsumfold(const int* __restrict__ cnt, int* __restrict__ bsum,
                           float* __restrict__ dis, const float* __restrict__ lastw,
                           const float* __restrict__ M1, const float* __restrict__ M2,
                           unsigned short* __restrict__ wb16) {
  int t = threadIdx.x;
  if (blockIdx.x < NB) {
    int idx = blockIdx.x * 256 + t;
    int v = (idx < NODES) ? cnt[idx] : 0;
    if (idx < NODES) dis[idx] = rsqrtf((float)(v + 1));  // +1 = self loop
    int s = v;
#pragma unroll
    for (int d = 1; d < 64; d <<= 1) s += __shfl_down(s, d, 64);
    __shared__ int wsum[4];
    if ((t & 63) == 0) wsum[t >> 6] = s;
    __syncthreads();
    if (t == 0) bsum[blockIdx.x] = wsum[0] + wsum[1] + wsum[2] + wsum[3];
  } else {
    int g = (blockIdx.x - NB) * 256 + t;  // [0, 8192)
    int o = g >> 6, j = g & 63;
    float s = 0.f;
    for (int k = 0; k < 64; ++k) {
      s += lastw[o * 128 + k] * M1[k * 64 + j];
      s += lastw[o * 128 + 64 + k] * M2[k * 64 + j];
    }
    wb16[4096 + g] = f2bf(s);
  }
}

__global__ void k_bscan(const int* __restrict__ bsum, int* __restrict__ boff) {
  int t = threadIdx.x;  // 128
  int lane = t & 63, w = t >> 6;
  int v = (t < NB) ? bsum[t] : 0;
  int inc = v;
#pragma unroll
  for (int d = 1; d < 64; d <<= 1) {
    int n = __shfl_up(inc, d, 64);
    if (lane >= d) inc += n;
  }
  __shared__ int ws0;
  if (w == 0 && lane == 63) ws0 = inc;
  __syncthreads();
  int off = (w == 1) ? ws0 : 0;
  if (t < NB) boff[t] = off + inc - v;
}

// ---------------- rowptr (blocks <79) + x*dis -> bf16 xs (blocks >=79) ----------------
__global__ void k_rowptr_xconv(const int* __restrict__ cnt, const int* __restrict__ boff,
                               int* __restrict__ rowptr, int* __restrict__ fill,
                               const float* __restrict__ x, const float* __restrict__ dis,
                               unsigned short* __restrict__ xs) {
  int t = threadIdx.x;
  if (blockIdx.x < NB) {
    int idx = blockIdx.x * 256 + t;
    int v = (idx < NODES) ? cnt[idx] : 0;
    int lane = t & 63, w = t >> 6;
    int inc = v;
#pragma unroll
    for (int d = 1; d < 64; d <<= 1) {
      int n = __shfl_up(inc, d, 64);
      if (lane >= d) inc += n;
    }
    __shared__ int wsum[4];
    if (lane == 63) wsum[w] = inc;
    __syncthreads();
    int wo = 0;
#pragma unroll
    for (int i = 0; i < 4; ++i)
      if (i < w) wo += wsum[i];
    int r = boff[blockIdx.x] + wo + inc - v;
    if (idx < NODES) {
      rowptr[idx] = r;
      fill[idx] = r;
      if (idx == NODES - 1) rowptr[NODES] = r + v;
    }
  } else {
    int g = (blockIdx.x - NB) * 256 + t;  // [0, NODES*64)
    int n = g >> 6, i = g & 63;
    int b = i >> 4, c = (i & 15) * 4;
    float ds = dis[n];
    float4 v = *(const float4*)(x + ((size_t)b * NODES + n) * 64 + c);
    ushort4 o;
    o.x = f2bf(v.x * ds); o.y = f2bf(v.y * ds);
    o.z = f2bf(v.z * ds); o.w = f2bf(v.w * ds);
    *(ushort4*)(xs + (size_t)n * 256 + i * 4) = o;
  }
}

__global__ void k_fill(const int* __restrict__ ei, int* __restrict__ fill,
                       int* __restrict__ csr_src) {
  int i = blockIdx.x * blockDim.x + threadIdx.x;
  if (i < NEDGE) {
    int row = ei[i];
    int col = ei[NEDGE + i];
    int pos = atomicAdd(&fill[col], 1);
    csr_src[pos] = row;
  }
}

// ---------------- fused gather + lin + sigmoid + BigW + relu ----------------
// block = 16 nodes (64 rows), 4 waves; wave gathers 4 nodes, then:
//   stage1 (swapped): h^T[feat][row] = lin @ xa^T  (wave w -> feats 16w..16w+15)
//   fst = sigmoid(h*dis+bias) -> LDS (packed ushort4 writes)
//   stage2 (swapped): out^T[oc][row] = BigW @ fst^T (wave w -> oc 32w..32w+31)
__global__ __launch_bounds__(256) void k_gpost(const int* __restrict__ rowptr,
                                               const int* __restrict__ csr_src,
                                               const unsigned short* __restrict__ xs,
                                               const float* __restrict__ dis,
                                               const float* __restrict__ bias,
                                               const unsigned short* __restrict__ wb16,
                                               float* __restrict__ out) {
  __shared__ unsigned short xa[64][72];
  __shared__ unsigned short fst[64][72];
  int t = threadIdx.x;
  int w = t >> 6, l = t & 63;
  int n0 = blockIdx.x * 16;

  // gather phase: wave w handles nodes n0+4w .. n0+4w+3
  for (int j = 0; j < 4; ++j) {
    int n = n0 + 4 * w + j;
    int beg = rowptr[n], end = rowptr[n + 1];
    int off = l * 4;
    ushort4 s = *(const ushort4*)(xs + (size_t)n * 256 + off);  // self loop
    float a0 = bf2f(s.x), a1 = bf2f(s.y), a2 = bf2f(s.z), a3 = bf2f(s.w);
    int i = beg;
    for (; i + 4 <= end; i += 4) {
      int r0 = csr_src[i], r1 = csr_src[i + 1], r2 = csr_src[i + 2], r3 = csr_src[i + 3];
      ushort4 v0 = *(const ushort4*)(xs + (size_t)r0 * 256 + off);
      ushort4 v1 = *(const ushort4*)(xs + (size_t)r1 * 256 + off);
      ushort4 v2 = *(const ushort4*)(xs + (size_t)r2 * 256 + off);
      ushort4 v3 = *(const ushort4*)(xs + (size_t)r3 * 256 + off);
      a0 += bf2f(v0.x) + bf2f(v1.x) + bf2f(v2.x) + bf2f(v3.x);
      a1 += bf2f(v0.y) + bf2f(v1.y) + bf2f(v2.y) + bf2f(v3.y);
      a2 += bf2f(v0.z) + bf2f(v1.z) + bf2f(v2.z) + bf2f(v3.z);
      a3 += bf2f(v0.w) + bf2f(v1.w) + bf2f(v2.w) + bf2f(v3.w);
    }
    for (; i < end; ++i) {
      int r = csr_src[i];
      ushort4 v = *(const ushort4*)(xs + (size_t)r * 256 + off);
      a0 += bf2f(v.x); a1 += bf2f(v.y); a2 += bf2f(v.z); a3 += bf2f(v.w);
    }
    ushort4 o;
    o.x = f2bf(a0); o.y = f2bf(a1); o.z = f2bf(a2); o.w = f2bf(a3);
    // row in tile = node_local*4 + batch; node_local = 4w+j, batch = l>>4
    *(ushort4*)&xa[16 * w + 4 * j + (l >> 4)][(l & 15) * 4] = o;
  }
  __syncthreads();

  int m = l & 15, q = l >> 4;
  const unsigned short* wlin = wb16;
  const unsigned short* bigw = wb16 + 4096;

  // stage1: D[feat=16w+4q+reg][row=16nt+m]
  f32x4 acc1[4] = {{0,0,0,0},{0,0,0,0},{0,0,0,0},{0,0,0,0}};
#pragma unroll
  for (int kk = 0; kk < 2; ++kk) {
    bf16x8 a = *(const bf16x8*)(wlin + (16 * w + m) * 64 + q * 8 + 32 * kk);
#pragma unroll
    for (int nt = 0; nt < 4; ++nt) {
      bf16x8 b = *(const bf16x8*)&xa[16 * nt + m][q * 8 + 32 * kk];
      acc1[nt] = __builtin_amdgcn_mfma_f32_16x16x32_bf16(a, b, acc1[nt], 0, 0, 0);
    }
  }
  float4 b4 = *(const float4*)(bias + 16 * w + 4 * q);
#pragma unroll
  for (int nt = 0; nt < 4; ++nt) {
    int row = 16 * nt + m;
    float ds = dis[n0 + (row >> 2)];
    float v0 = acc1[nt][0] * ds + b4.x;
    float v1 = acc1[nt][1] * ds + b4.y;
    float v2 = acc1[nt][2] * ds + b4.z;
    float v3 = acc1[nt][3] * ds + b4.w;
    ushort4 o;
    o.x = f2bf(1.f / (1.f + __expf(-v0)));
    o.y = f2bf(1.f / (1.f + __expf(-v1)));
    o.z = f2bf(1.f / (1.f + __expf(-v2)));
    o.w = f2bf(1.f / (1.f + __expf(-v3)));
    *(ushort4*)&fst[row][16 * w + 4 * q] = o;
  }
  __syncthreads();

  // stage2: D[oc=32w+16mt+4q+reg][row=16nt+m]
  f32x4 acc2[2][4] = {{{0,0,0,0},{0,0,0,0},{0,0,0,0},{0,0,0,0}},
                      {{0,0,0,0},{0,0,0,0},{0,0,0,0},{0,0,0,0}}};
#pragma unroll
  for (int kk = 0; kk < 2; ++kk) {
#pragma unroll
    for (int mt = 0; mt < 2; ++mt) {
      bf16x8 a = *(const bf16x8*)(bigw + (32 * w + 16 * mt + m) * 64 + q * 8 + 32 * kk);
#pragma unroll
      for (int nt = 0; nt < 4; ++nt) {
        bf16x8 b = *(const bf16x8*)&fst[16 * nt + m][q * 8 + 32 * kk];
        acc2[mt][nt] = __builtin_amdgcn_mfma_f32_16x16x32_bf16(a, b, acc2[mt][nt], 0, 0, 0);
      }
    }
  }
#pragma unroll
  for (int mt = 0; mt < 2; ++mt)
#pragma unroll
    for (int nt = 0; nt < 4; ++nt) {
      int row = 16 * nt + m;
      int n = n0 + (row >> 2), b = row & 3;
      int oc = 32 * w + 16 * mt + 4 * q;
      float4 v;
      v.x = acc2[mt][nt][0] > 0.f ? acc2[mt][nt][0] : 0.f;
      v.y = acc2[mt][nt][1] > 0.f ? acc2[mt][nt][1] : 0.f;
      v.z = acc2[mt][nt][2] > 0.f ? acc2[mt][nt][2] : 0.f;
      v.w = acc2[mt][nt][3] > 0.f ? acc2[mt][nt][3] : 0.f;
      *(float4*)(out + ((size_t)b * NODES + n) * 128 + oc) = v;
    }
}

extern "C" void kernel_launch(void* const* d_in, const int* in_sizes, int n_in,
                              void* d_out, int out_size, void* d_ws, size_t ws_size,
                              hipStream_t stream) {
  const float* x     = (const float*)d_in[0];
  const int*   ei    = (const int*)d_in[1];
  const float* lin_w = (const float*)d_in[2];
  const float* bias  = (const float*)d_in[3];
  const float* up1   = (const float*)d_in[4];
  const float* up2   = (const float*)d_in[5];
  const float* lo1   = (const float*)d_in[6];
  const float* lo2   = (const float*)d_in[7];
  const float* lastw = (const float*)d_in[8];
  float* out = (float*)d_out;

  char* ws = (char*)d_ws;
  unsigned short* wb16 = (unsigned short*)(ws);        // 12288 bf16 = 24576 B
  float* M1      = (float*)(ws + (32 << 10));          // 16 KB
  float* M2      = (float*)(ws + (48 << 10));          // 16 KB
  float* dis     = (float*)(ws + (64 << 10));          // 80 KB
  int*   cnt     = (int*)(ws + (192 << 10));           // 80 KB
  int*   rowptr  = (int*)(ws + (320 << 10));           // 80 KB+
  int*   fill    = (int*)(ws + (448 << 10));           // 80 KB
  int*   bsum    = (int*)(ws + (576 << 10));
  int*   boff    = (int*)(ws + (580 << 10));
  int*   csr_src = (int*)(ws + (1 << 20));             // 1.28 MB
  unsigned short* xs = (unsigned short*)(ws + (4 << 20));  // 10.24 MB

  k_prep<<<(12288 + NODES + 255) / 256, 256, 0, stream>>>(lin_w, up1, up2, lo1, lo2,
                                                          wb16, M1, M2, cnt);
  k_hist<<<(NEDGE + 255) / 256, 256, 0, stream>>>(ei, cnt);
  k_bsumfold<<<NB + 32, 256, 0, stream>>>(cnt, bsum, dis, lastw, M1, M2, wb16);
  k_bscan<<<1, 128, 0, stream>>>(bsum, boff);
  k_rowptr_xconv<<<NB + NODES / 4, 256, 0, stream>>>(cnt, boff, rowptr, fill, x, dis, xs);
  k_fill<<<(NEDGE + 255) / 256, 256, 0, stream>>>(ei, fill, csr_src);
  k_gpost<<<NODES / 16, 256, 0, stream>>>(rowptr, csr_src, xs, dis, bias, wb16, out);
}